// Round 8
// baseline (245.165 us; speedup 1.0000x reference)
//
#include <hip/hip_runtime.h>

// R8: ctx-split attention — problem only has 2048 q-waves (2/SIMD); max-free
// softmax lets chunks combine as plain sums, so split ctx into 3 chunks
// (singer, audio-half0, audio-half1) -> 1536 blocks, 4 blocks/CU co-resident.
// Blocks write unnormalized bf16 o-partials + fp32 li; combine kernel builds y.
// GEMM/cast side identical to R7 (next round profiles them).
#define DIM 512
#define NQ 2048
#define MA 2048
#define MS 256
#define QSCALE 0.06375864651f  // 512^-0.5 * log2(e)
#define OPSZ (4 * 2048 * 512)  // per-chunk o-partial elems (bf16)
#define LISZ (4 * 8 * 2048)    // per-chunk li elems (fp32)

typedef __attribute__((ext_vector_type(8))) short bf16x8;
typedef __attribute__((ext_vector_type(4))) float f32x4;
typedef __attribute__((ext_vector_type(16))) float f32x16;

__device__ __forceinline__ ushort f2b(float f) {
    uint u = __float_as_uint(f);
    u = (u + 0x7fffu + ((u >> 16) & 1u)) >> 16;
    return (ushort)u;
}

__device__ __forceinline__ uint pk2bf(float a, float b) {
#if __has_builtin(__builtin_amdgcn_cvt_pk_bf16_f32)
    typedef __attribute__((ext_vector_type(2))) __bf16 bf2;
    bf2 r = __builtin_amdgcn_cvt_pk_bf16_f32(a, b);
    uint u;
    __builtin_memcpy(&u, &r, 4);
    return u;
#else
    return ((__float_as_uint(a) + 0x8000u) >> 16) |
           ((__float_as_uint(b) + 0x8000u) & 0xffff0000u);
#endif
}

__device__ __forceinline__ float fexp2(float x) {
#if __has_builtin(__builtin_amdgcn_exp2f)
    return __builtin_amdgcn_exp2f(x);
#else
    return exp2f(x);
#endif
}

__device__ __forceinline__ void gload16(const ushort* g, ushort* l) {
    __builtin_amdgcn_global_load_lds(
        (const __attribute__((address_space(1))) void*)g,
        (__attribute__((address_space(3))) void*)l, 16, 0, 0);
}

// ---- fused cast: 6 weights + x + ac + scx -> contiguous bf16 region ----
__global__ __launch_bounds__(256) void cast_all(const float* __restrict__ w0,
                                                const float* __restrict__ w1,
                                                const float* __restrict__ w2,
                                                const float* __restrict__ w3,
                                                const float* __restrict__ w4,
                                                const float* __restrict__ w5,
                                                const float* __restrict__ x,
                                                const float* __restrict__ ac,
                                                const float* __restrict__ scx,
                                                ushort* __restrict__ dst) {
    int i = blockIdx.x * 256 + threadIdx.x;  // float4 index, 2621440 total
    const float* s;
    int o;
    if (i < 393216) {
        int w = i >> 16;
        s = w < 3 ? (w == 0 ? w0 : (w == 1 ? w1 : w2))
                  : (w == 3 ? w3 : (w == 4 ? w4 : w5));
        o = i & 65535;
    } else if (i < 1441792) { s = x;   o = i - 393216; }
    else if (i < 2490368)   { s = ac;  o = i - 1441792; }
    else                    { s = scx; o = i - 2490368; }
    float4 v = ((const float4*)s)[o];
    ushort4 u;
    u.x = f2b(v.x); u.y = f2b(v.y); u.z = f2b(v.z); u.w = f2b(v.w);
    ((ushort4*)dst)[i] = u;
}

// ---- fused GEMM: C = A @ B^T + bias, 128x128 tile, BK=32 ----
struct GD {
    const ushort* A; const ushort* B; const float* bias; void* out;
    long sB, sO;
    int N, bx, by, blk0, biasrow, scaleq, outf32, pad;
};

__global__ __launch_bounds__(256) void gemm_fused(GD d0, GD d1, GD d2, GD d3, GD d4) {
    __shared__ ushort At[128 * 32];
    __shared__ ushort Bt[128 * 32];
    GD d = d0;
    int bid = blockIdx.x;
    if (bid >= d1.blk0) d = d1;
    if (bid >= d2.blk0) d = d2;
    if (bid >= d3.blk0) d = d3;
    if (bid >= d4.blk0) d = d4;
    int local = bid - d.blk0;
    int x = local % d.bx;
    int rem = local / d.bx;
    int y = rem % d.by;
    int z = rem / d.by;

    int t = threadIdx.x;
    int wv = t >> 6, ln = t & 63, l = ln & 15, g = ln >> 4;
    int wrow = wv & 1, wcol = wv >> 1;
    int row0 = x * 128, col0 = y * 128;
    int srow = t >> 2;
    int slot = (t & 3) * 8;
    int sko = ((t ^ srow) & 3) * 8;        // XOR-swizzled global k-chunk
    int kc8 = ((g ^ (l & 3)) & 3) * 8;     // reader un-swizzle
    const ushort* Ab = d.A;
    const ushort* Bb = d.B + (size_t)z * d.sB;
    int N = d.N;

    f32x4 acc[4][4];
#pragma unroll
    for (int i = 0; i < 4; i++)
#pragma unroll
        for (int j = 0; j < 4; j++) acc[i][j] = (f32x4){0, 0, 0, 0};

    for (int k0 = 0; k0 < 512; k0 += 32) {
        __syncthreads();
#pragma unroll
        for (int c = 0; c < 2; c++) {
            gload16(Ab + (size_t)(row0 + srow + 64 * c) * 512 + k0 + sko,
                    At + (srow + 64 * c) * 32 + slot);
            gload16(Bb + (size_t)(col0 + srow + 64 * c) * 512 + k0 + sko,
                    Bt + (srow + 64 * c) * 32 + slot);
        }
        __syncthreads();
        bf16x8 ar[4], br[4];
#pragma unroll
        for (int i = 0; i < 4; i++)
            ar[i] = *(const bf16x8*)(At + (wrow * 64 + i * 16 + l) * 32 + kc8);
#pragma unroll
        for (int j = 0; j < 4; j++)
            br[j] = *(const bf16x8*)(Bt + (wcol * 64 + j * 16 + l) * 32 + kc8);
#pragma unroll
        for (int i = 0; i < 4; i++)
#pragma unroll
            for (int j = 0; j < 4; j++)
                acc[i][j] = __builtin_amdgcn_mfma_f32_16x16x32_bf16(ar[i], br[j], acc[i][j], 0, 0, 0);
    }
#pragma unroll
    for (int i = 0; i < 4; i++) {
#pragma unroll
        for (int j = 0; j < 4; j++) {
            int row = row0 + wrow * 64 + i * 16 + g * 4;
            int col = col0 + wcol * 64 + j * 16 + l;
#pragma unroll
            for (int r = 0; r < 4; r++) {
                float bv = d.biasrow ? d.bias[row + r] : d.bias[col];
                float o = acc[i][j][r] + bv;
                if (d.scaleq) o *= QSCALE;
                if (d.outf32)
                    ((float*)d.out + (size_t)z * d.sO)[(size_t)(row + r) * N + col] = o;
                else
                    ((ushort*)d.out + (size_t)z * d.sO)[(size_t)(row + r) * N + col] = f2b(o);
            }
        }
    }
}

// ---- attention partial: one ctx chunk per block; 32x32x16, K/V dbuf LDS,
// P in registers via PV k-permutation (R7). Writes unnormalized o + li. ----
__device__ __forceinline__ void attn_ctx32(const ushort* __restrict__ kg,
                                           const ushort* __restrict__ vg,
                                           int nt, int Ms, const bf16x8 (&aq)[4],
                                           ushort* __restrict__ Kl,
                                           ushort* __restrict__ Vl,
                                           f32x16 (&o)[2], float& li,
                                           int l5, int hi, int sr, int sc, int vbase) {
    bf16x8 k0 = *(const bf16x8*)kg;
    bf16x8 k1 = *(const bf16x8*)(kg + (size_t)32 * DIM);
    bf16x8 v0 = *(const bf16x8*)vg;
    bf16x8 v1 = *(const bf16x8*)(vg + (size_t)32 * Ms);
    __syncthreads();
    {   // tile 0 -> buf 0
        *(bf16x8*)(Kl + sr * 72 + sc) = k0;
        *(bf16x8*)(Kl + (sr + 32) * 72 + sc) = k1;
        union { bf16x8 v; uint2 h[2]; } cv;
        cv.v = v0;
        *(uint2*)(Vl + sr * 72 + vbase) = cv.h[0];
        *(uint2*)(Vl + sr * 72 + vbase + 8) = cv.h[1];
        cv.v = v1;
        *(uint2*)(Vl + (sr + 32) * 72 + vbase) = cv.h[0];
        *(uint2*)(Vl + (sr + 32) * 72 + vbase + 8) = cv.h[1];
    }
    if (nt > 1) {
        k0 = *(const bf16x8*)(kg + (size_t)64 * DIM);
        k1 = *(const bf16x8*)(kg + (size_t)96 * DIM);
        v0 = *(const bf16x8*)(vg + 64);
        v1 = *(const bf16x8*)(vg + (size_t)32 * Ms + 64);
    }
    for (int i = 0; i < nt; i++) {
        __syncthreads();
        if (i + 1 < nt) {
            ushort* Kb = Kl + ((i + 1) & 1) * (64 * 72);
            ushort* Vb = Vl + ((i + 1) & 1) * (64 * 72);
            *(bf16x8*)(Kb + sr * 72 + sc) = k0;
            *(bf16x8*)(Kb + (sr + 32) * 72 + sc) = k1;
            union { bf16x8 v; uint2 h[2]; } cv;
            cv.v = v0;
            *(uint2*)(Vb + sr * 72 + vbase) = cv.h[0];
            *(uint2*)(Vb + sr * 72 + vbase + 8) = cv.h[1];
            cv.v = v1;
            *(uint2*)(Vb + (sr + 32) * 72 + vbase) = cv.h[0];
            *(uint2*)(Vb + (sr + 32) * 72 + vbase + 8) = cv.h[1];
        }
        if (i + 2 < nt) {
            size_t off = (size_t)(i + 2) * 64;
            k0 = *(const bf16x8*)(kg + off * DIM);
            k1 = *(const bf16x8*)(kg + (off + 32) * DIM);
            v0 = *(const bf16x8*)(vg + off);
            v1 = *(const bf16x8*)(vg + (size_t)32 * Ms + off);
        }
        const ushort* Kc = Kl + (i & 1) * (64 * 72);
        const ushort* Vc = Vl + (i & 1) * (64 * 72);
        uint2 pq[2][4];
#pragma unroll
        for (int c = 0; c < 2; c++) {
            bf16x8 kf[4];
#pragma unroll
            for (int kd = 0; kd < 4; kd++)
                kf[kd] = *(const bf16x8*)(Kc + (32 * c + l5) * 72 + kd * 16 + hi * 8);
            f32x16 s;
#pragma unroll
            for (int ii = 0; ii < 16; ii++) s[ii] = 0.f;
#pragma unroll
            for (int kd = 0; kd < 4; kd++)
                s = __builtin_amdgcn_mfma_f32_32x32x16_bf16(kf[kd], aq[kd], s, 0, 0, 0);
#pragma unroll
            for (int m = 0; m < 4; m++) {
                float p0 = fexp2(s[4 * m + 0]);
                float p1 = fexp2(s[4 * m + 1]);
                float p2 = fexp2(s[4 * m + 2]);
                float p3 = fexp2(s[4 * m + 3]);
                li += (p0 + p1) + (p2 + p3);
                pq[c][m].x = pk2bf(p0, p1);
                pq[c][m].y = pk2bf(p2, p3);
            }
        }
#pragma unroll
        for (int kc = 0; kc < 4; kc++) {
            int c = kc >> 1, m0 = 2 * (kc & 1);
            union { bf16x8 v; uint u[4]; } w;
            w.u[0] = pq[c][m0].x;     w.u[1] = pq[c][m0].y;
            w.u[2] = pq[c][m0 + 1].x; w.u[3] = pq[c][m0 + 1].y;
#pragma unroll
            for (int dn = 0; dn < 2; dn++) {
                bf16x8 vf = *(const bf16x8*)(Vc + (32 * dn + l5) * 72 + kc * 16 + hi * 8);
                o[dn] = __builtin_amdgcn_mfma_f32_32x32x16_bf16(w.v, vf, o[dn], 0, 0, 0);
            }
        }
    }
}

__global__ __launch_bounds__(256) void attn_kernel(const ushort* __restrict__ q,
                                                   const ushort* __restrict__ Ka,
                                                   const ushort* __restrict__ VTa,
                                                   const ushort* __restrict__ Ks,
                                                   const ushort* __restrict__ VTs,
                                                   ushort* __restrict__ op,
                                                   float* __restrict__ Li) {
    __shared__ ushort Kl[2 * 64 * 72];
    __shared__ ushort Vl[2 * 64 * 72];
    int t = threadIdx.x;
    int wv = t >> 6, ln = t & 63, l5 = ln & 31, hi = ln >> 5;
    int h = blockIdx.y;
    int z = blockIdx.z;
    int bi = z / 3, chunk = z - 3 * bi;
    int q0 = blockIdx.x * 128 + wv * 32;
    bf16x8 aq[4];
    const ushort* qp = q + (size_t)(bi * NQ + q0 + l5) * DIM + h * 64 + hi * 8;
#pragma unroll
    for (int kd = 0; kd < 4; kd++) aq[kd] = *(const bf16x8*)(qp + kd * 16);
    int sr = t >> 3, sc = (t & 7) * 8;
    int vbase = (sc >> 4) * 16 + ((sc >> 3) & 1) * 4;  // permuted V slot base

    const ushort *kg, *vg;
    int nt, Ms;
    if (chunk == 0) {
        kg = Ks + (size_t)bi * MS * DIM;
        vg = VTs + (size_t)bi * DIM * MS;
        nt = 4; Ms = MS;
    } else {
        int c0 = (chunk - 1) * 1024;
        kg = Ka + (size_t)bi * MA * DIM + (size_t)c0 * DIM;
        vg = VTa + (size_t)bi * DIM * MA + c0;
        nt = 16; Ms = MA;
    }
    kg += (size_t)sr * DIM + h * 64 + sc;
    vg += (size_t)(h * 64 + sr) * Ms + sc;

    f32x16 o[2];
#pragma unroll
    for (int dn = 0; dn < 2; dn++)
#pragma unroll
        for (int i = 0; i < 16; i++) o[dn][i] = 0.f;
    float li = 0.f;

    attn_ctx32(kg, vg, nt, Ms, aq, Kl, Vl, o, li, l5, hi, sr, sc, vbase);
    li += __shfl_xor(li, 32);
    if (hi == 0)
        Li[(size_t)chunk * LISZ + ((size_t)bi * 8 + h) * 2048 + q0 + l5] = li;

    ushort* ob = op + (size_t)chunk * OPSZ;
#pragma unroll
    for (int dn = 0; dn < 2; dn++)
#pragma unroll
        for (int rg = 0; rg < 16; rg++) {
            int qr = (rg & 3) + 8 * (rg >> 2) + 4 * hi;
            ob[(size_t)(bi * NQ + q0 + qr) * DIM + h * 64 + 32 * dn + l5] = f2b(o[dn][rg]);
        }
}

// ---- combine: y = o_s/l_s + (o_a0+o_a1)/(l_a0+l_a1), bf16x8 per thread ----
__global__ __launch_bounds__(256) void combine(const ushort* __restrict__ op,
                                               const float* __restrict__ Li,
                                               ushort* __restrict__ y) {
    int i = blockIdx.x * 256 + threadIdx.x;   // uint4 index, 524288 total
    int gid = i << 3;
    int row = gid >> 9;       // 0..8191
    int bi = row >> 11;
    int qq = row & 2047;
    int c = gid & 511;
    int h = c >> 6;
    size_t lix = ((size_t)bi * 8 + h) * 2048 + qq;
    float ls = Li[lix];
    float la = Li[LISZ + lix] + Li[2 * LISZ + lix];
    float is_ = 1.f / ls, ia = 1.f / la;
    uint4 u0 = ((const uint4*)op)[i];
    uint4 u1 = ((const uint4*)(op + OPSZ))[i];
    uint4 u2 = ((const uint4*)(op + 2 * OPSZ))[i];
    uint4 r;
    const uint* p0 = &u0.x;
    const uint* p1 = &u1.x;
    const uint* p2 = &u2.x;
    uint* pr = &r.x;
#pragma unroll
    for (int j = 0; j < 4; j++) {
        float s_lo = __uint_as_float(p0[j] << 16);
        float s_hi = __uint_as_float(p0[j] & 0xffff0000u);
        float a_lo = __uint_as_float(p1[j] << 16) + __uint_as_float(p2[j] << 16);
        float a_hi = __uint_as_float(p1[j] & 0xffff0000u) +
                     __uint_as_float(p2[j] & 0xffff0000u);
        pr[j] = pk2bf(s_lo * is_ + a_lo * ia, s_hi * is_ + a_hi * ia);
    }
    ((uint4*)y)[i] = r;
}

extern "C" void kernel_launch(void* const* d_in, const int* in_sizes, int n_in,
                              void* d_out, int out_size, void* d_ws, size_t ws_size,
                              hipStream_t stream) {
    const float* x   = (const float*)d_in[0];
    const float* ac  = (const float*)d_in[1];
    const float* scx = (const float*)d_in[2];
    const float* Wq  = (const float*)d_in[3];
    const float* bq  = (const float*)d_in[4];
    const float* Wka = (const float*)d_in[5];
    const float* bka = (const float*)d_in[6];
    const float* Wva = (const float*)d_in[7];
    const float* bva = (const float*)d_in[8];
    const float* Wks = (const float*)d_in[9];
    const float* bks = (const float*)d_in[10];
    const float* Wvs = (const float*)d_in[11];
    const float* bvs = (const float*)d_in[12];
    const float* Wp  = (const float*)d_in[13];
    const float* bp  = (const float*)d_in[14];

    ushort* wb   = (ushort*)d_ws;         // contiguous cast dst:
    ushort* wqb  = wb;                    // [6 weights][xb][acb][scxb]
    ushort* wkab = wb + 262144;
    ushort* wvab = wb + 2 * 262144;
    ushort* wksb = wb + 3 * 262144;
    ushort* wvsb = wb + 4 * 262144;
    ushort* wpb  = wb + 5 * 262144;
    ushort* xb   = wb + 6 * 262144;       // [8192][512]
    ushort* acb  = xb + 4194304;          // [8192][512]
    ushort* scxb = acb + 4194304;         // [1024][512]
    ushort* qb   = scxb + 524288;         // [8192][512] prescaled q
    ushort* kab  = qb + 4194304;          // [8192][512]
    ushort* vta  = kab + 4194304;         // [4][512][2048] V^T
    ushort* ksb  = vta + 4194304;         // [1024][512]
    ushort* vts  = ksb + 524288;          // [4][512][256]  V^T
    ushort* op   = vts + 524288;          // [3][8192][512] bf16 o-partials
    float*  Li   = (float*)(op + 3 * OPSZ);  // [3][4][8][2048] fp32
    ushort* yb   = xb;                    // alias: x dead after gemm_fused

    cast_all<<<10240, 256, 0, stream>>>(Wq, Wka, Wva, Wks, Wvs, Wp, x, ac, scx, wb);

    GD gq   = {xb,   wqb,  bq,  qb,  0, 0,               512,  64, 4,  0,   0, 1, 0, 0};
    GD gka  = {acb,  wkab, bka, kab, 0, 0,               512,  64, 4,  256, 0, 0, 0, 0};
    GD gvta = {wvab, acb,  bva, vta, 2048L * 512, 512L * 2048, 2048, 4, 16, 512, 1, 0, 0, 0};
    GD gks  = {scxb, wksb, bks, ksb, 0, 0,               512,  8,  4,  768, 0, 0, 0, 0};
    GD gvts = {wvsb, scxb, bvs, vts, 256L * 512, 512L * 256,   256,  4,  2,  800, 1, 0, 0, 0};
    gemm_fused<<<832, 256, 0, stream>>>(gq, gka, gvta, gks, gvts);

    attn_kernel<<<dim3(16, 8, 12), 256, 0, stream>>>(qb, kab, vta, ksb, vts, op, Li);
    combine<<<2048, 256, 0, stream>>>(op, Li, yb);

    GD gpr = {yb, wpb, bp, d_out, 0, 0, 512, 64, 4, 0, 0, 0, 1, 0};
    GD gnv = {nullptr, nullptr, nullptr, nullptr, 0, 0, 0, 1, 1, 1 << 30, 0, 0, 0, 0};
    gemm_fused<<<256, 256, 0, stream>>>(gpr, gnv, gnv, gnv, gnv);
}